// Round 1
// baseline (2746.428 us; speedup 1.0000x reference)
//
#include <hip/hip_runtime.h>

#define BATCH 1024
#define NQ 16
#define DEPTH 8
#define NCLASS 10
#define RSQRT2 0.70710678118654752440f

// amplitude index: idx[15:12] = tid[9:6] (wave bits), idx[11:6] = tid[5:0] (lane bits),
// idx[5:0] = r (register index). qubit q lives at idx bit (15-q).
// q0..q3 -> wave bits 3..0 ; q4..q9 -> lane bits 5..0 ; q10..q15 -> local bits 5..0.

// ---------- local-bit gates (pure register, fully unrolled) ----------
template<int B>
__device__ __forceinline__ void ry_local(float st[64], float c, float s) {
#pragma unroll
  for (int r = 0; r < 64; ++r) {
    if ((r & (1 << B)) == 0) {
      float v0 = st[r], v1 = st[r | (1 << B)];
      st[r]            = fmaf(c, v0, -s * v1);
      st[r | (1 << B)] = fmaf(s, v0,  c * v1);
    }
  }
}

template<int CB, int TB>
__device__ __forceinline__ void cnot_local(float st[64]) {
#pragma unroll
  for (int r = 0; r < 64; ++r) {
    if (((r >> CB) & 1) == 1 && ((r >> TB) & 1) == 0) {
      float t = st[r];
      st[r] = st[r | (1 << TB)];
      st[r | (1 << TB)] = t;
    }
  }
}

// ctrl = thread-uniform predicate, target = local bit TB
template<int TB>
__device__ __forceinline__ void cnot_tlocal(float st[64], bool pred) {
#pragma unroll
  for (int r = 0; r < 64; ++r) {
    if (((r >> TB) & 1) == 0) {
      int r1 = r | (1 << TB);
      float v0 = st[r], v1 = st[r1];
      st[r]  = pred ? v1 : v0;
      st[r1] = pred ? v0 : v1;
    }
  }
}

// ---------- lane-bit gates (cross-lane shuffle) ----------
template<int L>
__device__ __forceinline__ void ry_lane(float st[64], float c, float s, int lane) {
  float ss = ((lane >> L) & 1) ? s : -s;
#pragma unroll
  for (int r = 0; r < 64; ++r) {
    float p = __shfl_xor(st[r], 1 << L, 64);
    st[r] = fmaf(ss, p, c * st[r]);
  }
}

template<int L>
__device__ __forceinline__ void cnot_lane(float st[64], bool pred) {
#pragma unroll
  for (int r = 0; r < 64; ++r) {
    float p = __shfl_xor(st[r], 1 << L, 64);
    st[r] = pred ? p : st[r];
  }
}

// ---------- wave-bit gates (LDS exchange, 2 halves x 32 floats) ----------
// MODE 0 = RY (st = c*st + ss*partner), MODE 1 = CNOT (st = pred ? partner : st)
template<int W, int MODE>
__device__ __forceinline__ void wave_gate(float st[64], float* lds, int tid, int lane,
                                          float c, float ss, bool pred) {
  const int pt = tid ^ (64 << W);
#pragma unroll
  for (int h = 0; h < 2; ++h) {
    __syncthreads();   // protect previous LDS round / previous gate reads
#pragma unroll
    for (int j = 0; j < 8; ++j) {
      const int off = (4 * j + 4 * (lane & 7)) & 31;  // bank-spread rotation
      float4 v;
      v.x = st[h * 32 + 4 * j + 0];
      v.y = st[h * 32 + 4 * j + 1];
      v.z = st[h * 32 + 4 * j + 2];
      v.w = st[h * 32 + 4 * j + 3];
      *reinterpret_cast<float4*>(&lds[tid * 32 + off]) = v;
    }
    __syncthreads();
#pragma unroll
    for (int j = 0; j < 8; ++j) {
      const int off = (4 * j + 4 * (lane & 7)) & 31;
      float4 p = *reinterpret_cast<const float4*>(&lds[pt * 32 + off]);
      if (MODE == 0) {
        st[h*32+4*j+0] = fmaf(ss, p.x, c * st[h*32+4*j+0]);
        st[h*32+4*j+1] = fmaf(ss, p.y, c * st[h*32+4*j+1]);
        st[h*32+4*j+2] = fmaf(ss, p.z, c * st[h*32+4*j+2]);
        st[h*32+4*j+3] = fmaf(ss, p.w, c * st[h*32+4*j+3]);
      } else {
        st[h*32+4*j+0] = pred ? p.x : st[h*32+4*j+0];
        st[h*32+4*j+1] = pred ? p.y : st[h*32+4*j+1];
        st[h*32+4*j+2] = pred ? p.z : st[h*32+4*j+2];
        st[h*32+4*j+3] = pred ? p.w : st[h*32+4*j+3];
      }
    }
  }
}

template<int W>
__device__ __forceinline__ void ry_wave(float st[64], float* lds, int tid, int lane,
                                        float c, float s) {
  float ss = ((tid >> (6 + W)) & 1) ? s : -s;
  wave_gate<W, 0>(st, lds, tid, lane, c, ss, false);
}

template<int W>
__device__ __forceinline__ void cnot_wave(float st[64], float* lds, int tid, int lane, bool pred) {
  wave_gate<W, 1>(st, lds, tid, lane, 0.f, 0.f, pred);
}

__global__ __launch_bounds__(1024, 4) void vqc_kernel(const float* __restrict__ x,
                                                      const float* __restrict__ w,
                                                      float* __restrict__ out) {
  extern __shared__ float lds[];  // 1024*32 floats = 128 KB
  const int tid  = (int)threadIdx.x;
  const int lane = tid & 63;
  const int b    = (int)blockIdx.x;

  float st[64];

  // ---------- encoding: H + RY(x_q) is a product state ----------
  {
    float T = 1.0f;
#pragma unroll
    for (int q = 0; q <= 9; ++q) {  // thread-level qubits: tid bit (9-q)
      float th = 0.5f * x[b * NQ + q];
      float c = __cosf(th), s = __sinf(th);
      float f0 = (c - s) * RSQRT2;
      float f1 = (c + s) * RSQRT2;
      T *= ((tid >> (9 - q)) & 1) ? f1 : f0;
    }
    st[0] = T;
#pragma unroll
    for (int p = 0; p < 6; ++p) {   // local qubit q = 15-p at local bit p
      float th = 0.5f * x[b * NQ + (15 - p)];
      float c = __cosf(th), s = __sinf(th);
      float f0 = (c - s) * RSQRT2;
      float f1 = (c + s) * RSQRT2;
#pragma unroll
      for (int k = 0; k < 64; ++k) {
        if (k < (1 << p)) {
          float v = st[k];
          st[k]            = v * f0;
          st[k + (1 << p)] = v * f1;
        }
      }
    }
  }

  // ---------- depth loop (kept rolled to bound code size) ----------
#pragma clang loop unroll(disable)
  for (int d = 0; d < DEPTH; ++d) {
    const float* wrow = w + d * NQ;

    // CNOT evens: (0,1)(2,3)(4,5)(6,7)(8,9)(10,11)(12,13)(14,15)
    cnot_wave<2>(st, lds, tid, lane, ((tid >> 9) & 1) != 0);  // (0,1) ctrl wb3 tgt wb2
    cnot_wave<0>(st, lds, tid, lane, ((tid >> 7) & 1) != 0);  // (2,3) ctrl wb1 tgt wb0
    cnot_lane<4>(st, ((lane >> 5) & 1) != 0);                 // (4,5)
    cnot_lane<2>(st, ((lane >> 3) & 1) != 0);                 // (6,7)
    cnot_lane<0>(st, ((lane >> 1) & 1) != 0);                 // (8,9)
    cnot_local<5, 4>(st);                                     // (10,11)
    cnot_local<3, 2>(st);                                     // (12,13)
    cnot_local<1, 0>(st);                                     // (14,15)

    // CNOT odds: (1,2)(3,4)(5,6)(7,8)(9,10)(11,12)(13,14)
    cnot_wave<1>(st, lds, tid, lane, ((tid >> 8) & 1) != 0);  // (1,2) ctrl wb2 tgt wb1
    cnot_lane<5>(st, ((tid >> 6) & 1) != 0);                  // (3,4) ctrl wb0 tgt lb5
    cnot_lane<3>(st, ((lane >> 4) & 1) != 0);                 // (5,6)
    cnot_lane<1>(st, ((lane >> 2) & 1) != 0);                 // (7,8)
    cnot_tlocal<5>(st, (lane & 1) != 0);                      // (9,10) ctrl lb0 tgt local b5
    cnot_local<4, 3>(st);                                     // (11,12)
    cnot_local<2, 1>(st);                                     // (13,14)

    // RY layer: lane + local first (short c/s liveness), wave last
    float th, c, s;
#define RYCS(q) th = 0.5f * wrow[q]; c = __cosf(th); s = __sinf(th);
    RYCS(4)  ry_lane<5>(st, c, s, lane);
    RYCS(5)  ry_lane<4>(st, c, s, lane);
    RYCS(6)  ry_lane<3>(st, c, s, lane);
    RYCS(7)  ry_lane<2>(st, c, s, lane);
    RYCS(8)  ry_lane<1>(st, c, s, lane);
    RYCS(9)  ry_lane<0>(st, c, s, lane);
    RYCS(10) ry_local<5>(st, c, s);
    RYCS(11) ry_local<4>(st, c, s);
    RYCS(12) ry_local<3>(st, c, s);
    RYCS(13) ry_local<2>(st, c, s);
    RYCS(14) ry_local<1>(st, c, s);
    RYCS(15) ry_local<0>(st, c, s);
    RYCS(0)  ry_wave<3>(st, lds, tid, lane, c, s);
    RYCS(1)  ry_wave<2>(st, lds, tid, lane, c, s);
    RYCS(2)  ry_wave<1>(st, lds, tid, lane, c, s);
    RYCS(3)  ry_wave<0>(st, lds, tid, lane, c, s);
#undef RYCS
  }

  // ---------- measurement: <Z_q>, q = 0..9 (all thread-level bits) ----------
  float tot = 0.f;
#pragma unroll
  for (int r = 0; r < 64; ++r) tot = fmaf(st[r], st[r], tot);

  // 7 wave reductions: [0] unsigned total (for wave-bit classes 0..3),
  // [1..6] lane-bit-signed totals for classes 4..9 (sign bit: lane bit 9-q)
  float red[7];
  red[0] = tot;
#pragma unroll
  for (int q = 4; q <= 9; ++q)
    red[q - 3] = (((lane >> (9 - q)) & 1) != 0) ? -tot : tot;
#pragma unroll
  for (int i = 0; i < 7; ++i) {
#pragma unroll
    for (int m = 1; m < 64; m <<= 1)
      red[i] += __shfl_xor(red[i], m, 64);
  }

  __syncthreads();  // done with gate LDS usage
  if (lane == 0) {
    const int wv = tid >> 6;
#pragma unroll
    for (int i = 0; i < 7; ++i) lds[wv * 8 + i] = red[i];
  }
  __syncthreads();

  if (tid < NCLASS) {
    float acc = 0.f;
    if (tid < 4) {  // class qubit q=tid on wave bit (3-tid)
#pragma unroll
      for (int wv = 0; wv < 16; ++wv) {
        float v = lds[wv * 8];
        acc += (((wv >> (3 - tid)) & 1) != 0) ? -v : v;
      }
    } else {        // class qubit q=tid, signed partial at red[tid-3]
#pragma unroll
      for (int wv = 0; wv < 16; ++wv) acc += lds[wv * 8 + (tid - 3)];
    }
    out[b * NCLASS + tid] = acc;
  }
}

extern "C" void kernel_launch(void* const* d_in, const int* in_sizes, int n_in,
                              void* d_out, int out_size, void* d_ws, size_t ws_size,
                              hipStream_t stream) {
  (void)in_sizes; (void)n_in; (void)d_ws; (void)ws_size; (void)out_size;
  const float* x = (const float*)d_in[0];
  const float* w = (const float*)d_in[1];
  float* out = (float*)d_out;

  // 128 KB dynamic LDS (gfx950 has 160 KB/CU) — opt in every call (idempotent).
  hipFuncSetAttribute(reinterpret_cast<const void*>(vqc_kernel),
                      hipFuncAttributeMaxDynamicSharedMemorySize, 131072);

  vqc_kernel<<<BATCH, 1024, 131072, stream>>>(x, w, out);
}